// Round 4
// baseline (350.396 us; speedup 1.0000x reference)
//
#include <hip/hip_runtime.h>
#include <hip/hip_bf16.h>
#include <cstdint>
#include <cstddef>

// Problem constants (B,C,H,W)=(2,128,192,192), K=4, O=60
constexpr int kB = 2, kC = 128, kH = 192, kW = 192, kK = 4, kO = 60;
constexpr int kHW  = kH * kW;        // 36864
constexpr int NPIX = kB * kHW;       // 73728
constexpr int MT   = 64;             // consecutive pixels per tile
constexpr int TPB  = kHW / MT;       // tiles per batch image = 576
constexpr int NTILE = NPIX / MT;     // 1152
constexpr float kSlope = 0.01f;

typedef __attribute__((ext_vector_type(8))) short bf16x8;
typedef __attribute__((ext_vector_type(4))) float f32x4;

// ---------------- dtype helpers ----------------
__device__ __forceinline__ unsigned short f2bf(float f) {
  unsigned u = __float_as_uint(f);
  u += 0x7FFF + ((u >> 16) & 1);
  return (unsigned short)(u >> 16);
}
__device__ __forceinline__ float bf2f(unsigned short u) {
  return __uint_as_float(((unsigned)u) << 16);
}
__device__ __forceinline__ float load1(const float* p) { return *p; }
__device__ __forceinline__ float load1(const __hip_bfloat16* p) {
  return bf2f(*reinterpret_cast<const unsigned short*>(p));
}
__device__ __forceinline__ bf16x8 load_wfrag(const __hip_bfloat16* p) {
  return *reinterpret_cast<const bf16x8*>(p);
}
__device__ __forceinline__ bf16x8 load_wfrag(const float* p) {
  bf16x8 r;
#pragma unroll
  for (int j = 0; j < 8; ++j) r[j] = (short)f2bf(p[j]);
  return r;
}
__device__ __forceinline__ void store1(float* p, float v) { *p = v; }
__device__ __forceinline__ void store1(__hip_bfloat16* p, float v) {
  *reinterpret_cast<unsigned short*>(p) = f2bf(v);
}

// Swizzled LDS tile layout (no padding): element (pix, c) lives at
//   pix*kC + grp(pix, c>>3)*8 + (c&7)
// Rotation spreads the 16-byte groups across banks: b128 reads and the
// transpose writes are both ~2-way (free). All accesses stay 16B/8B aligned.
__device__ __forceinline__ int xgrp(int pix, int g) {
  return (g + pix + (pix >> 3)) & 15;
}

// ---------------- x tile staging (global coalesced -> swizzled LDS) ----------
__device__ __forceinline__ void stage_x(const __hip_bfloat16* xp, size_t base,
                                        unsigned short (*X)[kC], int tid) {
  const unsigned short* xs = reinterpret_cast<const unsigned short*>(xp);
#pragma unroll
  for (int i = 0; i < 4; ++i) {
    const int flat = i * 256 + tid;        // 0..1023
    const int c  = flat >> 3;              // channel 0..127
    const int P0 = (flat & 7) * 8;         // pixel base 0..56
    bf16x8 v = *reinterpret_cast<const bf16x8*>(xs + base + (size_t)c * kHW + P0);
#pragma unroll
    for (int j = 0; j < 8; ++j)
      X[P0 + j][xgrp(P0 + j, c >> 3) * 8 + (c & 7)] = (unsigned short)v[j];
  }
}
__device__ __forceinline__ void stage_x(const float* xp, size_t base,
                                        unsigned short (*X)[kC], int tid) {
#pragma unroll
  for (int i = 0; i < 8; ++i) {
    const int flat = i * 256 + tid;        // 0..2047
    const int c  = flat >> 4;              // channel 0..127
    const int P0 = (flat & 15) * 4;        // pixel base 0..60
    const float4 v = *reinterpret_cast<const float4*>(xp + base + (size_t)c * kHW + P0);
    const float vv[4] = {v.x, v.y, v.z, v.w};
#pragma unroll
    for (int j = 0; j < 4; ++j)
      X[P0 + j][xgrp(P0 + j, c >> 3) * 8 + (c & 7)] = f2bf(vv[j]);
  }
}

// ---------------- MFMA layer: dst = op(W @ src + b [+ dst]) ------------------
// A-frag = weight rows (global): A[m=lane&15][k=quad*8+j]
// B-frag = activation rows (LDS swizzled): B[n=pix][k]
// D: col=lane&15 (pixel), row=quad*4+reg (out channel) [m89-verified]
// RES reads the destination address itself (in-place residual; race-free:
// each (pix,channel) is owned by exactly one lane).
template<typename T, bool LRELU, bool RES>
__device__ __forceinline__ void layerD(const unsigned short (*src)[kC],
                                       unsigned short (*dst)[kC],
                                       const T* __restrict__ Wk,
                                       const T* __restrict__ bk, int tid) {
  const int wave = tid >> 6, lane = tid & 63, quad = lane >> 4, col = lane & 15;
  bf16x8 a[2][4];
  float bias[2][4];
#pragma unroll
  for (int oi = 0; oi < 2; ++oi) {
    const int row = (wave * 2 + oi) * 16 + col;
#pragma unroll
    for (int ks = 0; ks < 4; ++ks)
      a[oi][ks] = load_wfrag(Wk + (size_t)row * kC + ks * 32 + quad * 8);
#pragma unroll
    for (int r = 0; r < 4; ++r)
      bias[oi][r] = load1(bk + (wave * 2 + oi) * 16 + quad * 4 + r);
  }
#pragma unroll
  for (int pt = 0; pt < 4; ++pt) {
    const int pix = pt * 16 + col;
    bf16x8 b[4];
#pragma unroll
    for (int ks = 0; ks < 4; ++ks)
      b[ks] = *reinterpret_cast<const bf16x8*>(&src[pix][xgrp(pix, ks * 4 + quad) * 8]);
#pragma unroll
    for (int oi = 0; oi < 2; ++oi) {
      f32x4 acc = {0.f, 0.f, 0.f, 0.f};
#pragma unroll
      for (int ks = 0; ks < 4; ++ks)
        acc = __builtin_amdgcn_mfma_f32_16x16x32_bf16(a[oi][ks], b[ks], acc, 0, 0, 0);
      const int nb = (wave * 2 + oi) * 16 + quad * 4;
      unsigned short* dp = &dst[pix][xgrp(pix, nb >> 3) * 8 + (nb & 7)];
      float v[4];
#pragma unroll
      for (int r = 0; r < 4; ++r) {
        float t = acc[r] + bias[oi][r];
        if constexpr (LRELU) t = (t >= 0.f) ? t : kSlope * t;
        v[r] = t;
      }
      if constexpr (RES) {
        const short4 rv = *reinterpret_cast<const short4*>(dp);
        v[0] += bf2f((unsigned short)rv.x);
        v[1] += bf2f((unsigned short)rv.y);
        v[2] += bf2f((unsigned short)rv.z);
        v[3] += bf2f((unsigned short)rv.w);
      }
      short4 pk;
      pk.x = (short)f2bf(v[0]); pk.y = (short)f2bf(v[1]);
      pk.z = (short)f2bf(v[2]); pk.w = (short)f2bf(v[3]);
      *reinterpret_cast<short4*>(dp) = pk;
    }
  }
}

// final layer (60 outs): masked accumulate into persistent registers
template<typename T>
__device__ __forceinline__ void layer_outD(const unsigned short (*src)[kC],
                                           const T* __restrict__ Wk,
                                           const T* __restrict__ bk,
                                           int k, const int* clsv,
                                           float accf[4][4], int tid) {
  const int wave = tid >> 6, lane = tid & 63, quad = lane >> 4, col = lane & 15;
  bf16x8 a[4];
  const int row = min(wave * 16 + col, kO - 1);
#pragma unroll
  for (int ks = 0; ks < 4; ++ks)
    a[ks] = load_wfrag(Wk + (size_t)row * kC + ks * 32 + quad * 8);
  float bias[4];
#pragma unroll
  for (int r = 0; r < 4; ++r) {
    const int n = wave * 16 + quad * 4 + r;
    bias[r] = (n < kO) ? load1(bk + n) : 0.f;
  }
#pragma unroll
  for (int pt = 0; pt < 4; ++pt) {
    const int pix = pt * 16 + col;
    bf16x8 b[4];
#pragma unroll
    for (int ks = 0; ks < 4; ++ks)
      b[ks] = *reinterpret_cast<const bf16x8*>(&src[pix][xgrp(pix, ks * 4 + quad) * 8]);
    f32x4 acc = {0.f, 0.f, 0.f, 0.f};
#pragma unroll
    for (int ks = 0; ks < 4; ++ks)
      acc = __builtin_amdgcn_mfma_f32_16x16x32_bf16(a[ks], b[ks], acc, 0, 0, 0);
    if (clsv[pt] == k) {
#pragma unroll
      for (int r = 0; r < 4; ++r) accf[pt][r] += acc[r] + bias[r];
    }
  }
}

// ---------------- dense body: loop classes, mask at the end -----------------
template<typename T>
__device__ void body(const T* __restrict__ W1, const T* __restrict__ b1,
                     const T* __restrict__ Wr1, const T* __restrict__ br1,
                     const T* __restrict__ Wr2, const T* __restrict__ br2,
                     const T* __restrict__ W3, const T* __restrict__ b3,
                     const T* __restrict__ W4, const T* __restrict__ b4,
                     T* __restrict__ out, int bb, int hw0,
                     unsigned short (*X)[kC], unsigned short (*A)[kC],
                     unsigned short (*Bb)[kC], const int* cls, int tid) {
  const int col = tid & 15;
  int clsv[4];
#pragma unroll
  for (int pt = 0; pt < 4; ++pt) clsv[pt] = cls[pt * 16 + col];

  float accf[4][4];
#pragma unroll
  for (int pt = 0; pt < 4; ++pt)
#pragma unroll
    for (int r = 0; r < 4; ++r) accf[pt][r] = 0.f;

  for (int k = 0; k < kK; ++k) {
    const T* W1k  = W1  + (size_t)k * kC * kC;  const T* b1k  = b1  + (size_t)k * kC;
    const T* Wr1k = Wr1 + (size_t)k * kC * kC;  const T* br1k = br1 + (size_t)k * kC;
    const T* Wr2k = Wr2 + (size_t)k * kC * kC;  const T* br2k = br2 + (size_t)k * kC;
    const T* W3k  = W3  + (size_t)k * kC * kC;  const T* b3k  = b3  + (size_t)k * kC;
    const T* W4k  = W4  + (size_t)k * kO * kC;  const T* b4k  = b4  + (size_t)k * kO;

    layerD<T, false, false>(X,  A,  W1k,  b1k,  tid); __syncthreads(); // h
    layerD<T, true,  false>(A,  Bb, Wr1k, br1k, tid); __syncthreads(); // lrelu
    layerD<T, false, true >(Bb, A,  Wr2k, br2k, tid); __syncthreads(); // h += r
    layerD<T, true,  false>(A,  Bb, W3k,  b3k,  tid); __syncthreads(); // lrelu
    layer_outD<T>(Bb, W4k, b4k, k, clsv, accf, tid);
    __syncthreads();  // Bb reused as dst next class (L2 writes Bb)
  }

  // store: out[bb][n][hw0+pix], lanes over pixels => 32B-coalesced per quad
  const int wave = tid >> 6, quad = (tid & 63) >> 4;
#pragma unroll
  for (int pt = 0; pt < 4; ++pt) {
    const int pix = pt * 16 + col;
#pragma unroll
    for (int r = 0; r < 4; ++r) {
      const int n = wave * 16 + quad * 4 + r;
      if (n < kO)
        store1(out + ((size_t)bb * kO + n) * kHW + hw0 + pix, accf[pt][r]);
    }
  }
}

// ---------------- single fused kernel ----------------
__global__ __launch_bounds__(256, 3) void dense_chain(
    const void* x, const void* seg,
    const void* W1, const void* b1, const void* Wr1, const void* br1,
    const void* Wr2, const void* br2, const void* W3, const void* b3,
    const void* W4, const void* b4, void* out) {
  __shared__ unsigned short X[MT][kC];    // 16 KB, swizzled
  __shared__ unsigned short A[MT][kC];    // 16 KB
  __shared__ unsigned short Bb[MT][kC];   // 16 KB
  __shared__ int cls[MT];
  __shared__ int s_bad, s_onz;
  const int tid = threadIdx.x;

  if (tid == 0) { s_bad = 0; s_onz = 0; }
  __syncthreads();
  // dtype sniff from L2-hot first bytes:
  //  bf16 x: halves are N(0,1) values, exponent>=0x84 (|x|>=32) never occurs.
  //  f32  x: even halves are random mantissa bits -> ~48% "bad".
  {
    const unsigned short h = ((const unsigned short*)x)[tid];
    if (((h >> 7) & 0xFF) >= 0x84) atomicAdd(&s_bad, 1);
    if (tid < 128 && (tid & 1) && ((const unsigned*)seg)[tid] != 0)
      atomicAdd(&s_onz, 1);
  }
  __syncthreads();
  const bool isf32 = (s_bad > 8);
  const bool is64  = (s_onz == 0);   // int64 seg: odd 32-bit words all zero

  const int tile = blockIdx.x;
  const int bb   = tile / TPB;
  const int hw0  = (tile - bb * TPB) * MT;

  if (tid < MT) {
    const int p = bb * kHW + hw0 + tid;
    cls[tid] = is64 ? (int)((const long long*)seg)[p] : ((const int*)seg)[p];
  }
  const size_t base = (size_t)bb * kC * kHW + hw0;
  if (isf32) stage_x((const float*)x, base, X, tid);
  else       stage_x((const __hip_bfloat16*)x, base, X, tid);
  __syncthreads();

  if (isf32) {
    body<float>((const float*)W1, (const float*)b1,
                (const float*)Wr1, (const float*)br1,
                (const float*)Wr2, (const float*)br2,
                (const float*)W3, (const float*)b3,
                (const float*)W4, (const float*)b4,
                (float*)out, bb, hw0, X, A, Bb, cls, tid);
  } else {
    body<__hip_bfloat16>((const __hip_bfloat16*)W1, (const __hip_bfloat16*)b1,
                         (const __hip_bfloat16*)Wr1, (const __hip_bfloat16*)br1,
                         (const __hip_bfloat16*)Wr2, (const __hip_bfloat16*)br2,
                         (const __hip_bfloat16*)W3, (const __hip_bfloat16*)b3,
                         (const __hip_bfloat16*)W4, (const __hip_bfloat16*)b4,
                         (__hip_bfloat16*)out, bb, hw0, X, A, Bb, cls, tid);
  }
}

extern "C" void kernel_launch(void* const* d_in, const int* in_sizes, int n_in,
                              void* d_out, int out_size, void* d_ws, size_t ws_size,
                              hipStream_t stream) {
  (void)in_sizes; (void)n_in; (void)out_size; (void)d_ws; (void)ws_size;
  dense_chain<<<NTILE, 256, 0, stream>>>(
      d_in[0], d_in[1], d_in[2], d_in[3], d_in[4], d_in[5], d_in[6], d_in[7],
      d_in[8], d_in[9], d_in[10], d_in[11], d_out);
}

// Round 5
// 186.724 us; speedup vs baseline: 1.8765x; 1.8765x over previous
//
#include <hip/hip_runtime.h>
#include <hip/hip_bf16.h>
#include <cstdint>
#include <cstddef>

// Problem constants (B,C,H,W)=(2,128,192,192), K=4, O=60
constexpr int kB = 2, kC = 128, kH = 192, kW = 192, kK = 4, kO = 60;
constexpr int kHW  = kH * kW;        // 36864
constexpr int NPIX = kB * kHW;       // 73728
constexpr int MT   = 64;             // pixels per chain tile
constexpr int NBLK = NPIX / 256;     // 288 (prologue blocks)
constexpr int NT   = NPIX / MT;      // 1152
constexpr float kSlope = 0.01f;

// ws layout (ints):
//  [0..3]   class totals (scan)
//  [4],[5]  flags: isf32, seg-is-int64 (count blk 0)
//  [8..8+NBLK*4)  per-block per-class counts -> padded slot bases (scan)
//  [4096..4096+NPIX+256)  bucket: slot -> pixel id (+slack for padded reads)
//  byte ACT_OFF: Act0[(NT+kK)*MT][kC] bf16 rows (256 B each)
constexpr int WS_FLAGS  = 4;
constexpr int WS_CNT    = 8;
constexpr int WS_BUCKET = 4096;
constexpr size_t ACT_OFF   = (size_t)(WS_BUCKET + NPIX + 256) * 4;  // 312320, 256B-aligned
constexpr size_t ACT_BYTES = (size_t)(NT + kK) * MT * (kC * 2);

typedef __attribute__((ext_vector_type(8))) short bf16x8;
typedef __attribute__((ext_vector_type(4))) float f32x4;

// ---------------- dtype helpers ----------------
__device__ __forceinline__ unsigned short f2bf(float f) {
  unsigned u = __float_as_uint(f);
  u += 0x7FFF + ((u >> 16) & 1);
  return (unsigned short)(u >> 16);
}
__device__ __forceinline__ float bf2f(unsigned short u) {
  return __uint_as_float(((unsigned)u) << 16);
}
__device__ __forceinline__ float load1(const float* p) { return *p; }
__device__ __forceinline__ float load1(const __hip_bfloat16* p) {
  return bf2f(*reinterpret_cast<const unsigned short*>(p));
}
__device__ __forceinline__ unsigned short loadbf(const __hip_bfloat16* p) {
  return *reinterpret_cast<const unsigned short*>(p);
}
__device__ __forceinline__ unsigned short loadbf(const float* p) { return f2bf(*p); }
__device__ __forceinline__ bf16x8 load_wfrag(const __hip_bfloat16* p) {
  return *reinterpret_cast<const bf16x8*>(p);
}
__device__ __forceinline__ bf16x8 load_wfrag(const float* p) {
  bf16x8 r;
#pragma unroll
  for (int j = 0; j < 8; ++j) r[j] = (short)f2bf(p[j]);
  return r;
}
__device__ __forceinline__ void store1(float* p, float v) { *p = v; }
__device__ __forceinline__ void store1(__hip_bfloat16* p, float v) {
  *reinterpret_cast<unsigned short*>(p) = f2bf(v);
}

// LDS swizzle: row = 128 bf16 = 16 groups of 8; group g of row r lives at
// X[r][xgrp(r,g)*8]. b128 layer reads/writes land ~2-way (free, m136).
__device__ __forceinline__ int xgrp(int r, int g) {
  return (g + r + (r >> 3)) & 15;
}

// ---------------- kernel 1: per-block class count + dtype sniff -------------
__global__ void count_sniff(const void* xraw, const void* segraw, int* wsI) {
  __shared__ int lcnt[kK];
  __shared__ int s_bad, s_onz;
  const int tid = threadIdx.x;
  if (tid < kK) lcnt[tid] = 0;
  if (tid == 0) { s_bad = 0; s_onz = 0; }
  __syncthreads();
  // x: bf16 N(0,1) halves never have exponent>=0x84 (|x|>=32); f32 low halves do ~50%.
  const unsigned short h = ((const unsigned short*)xraw)[tid];
  if (((h >> 7) & 0xFF) >= 0x84) atomicAdd(&s_bad, 1);
  // seg: int64 -> odd 32-bit words all zero.
  if (tid < 128 && (tid & 1) && ((const unsigned*)segraw)[tid] != 0) atomicAdd(&s_onz, 1);
  __syncthreads();
  const bool is64 = (s_onz < 4);
  const int p = blockIdx.x * 256 + tid;
  const int k = is64 ? (int)((const long long*)segraw)[p] : ((const int*)segraw)[p];
  atomicAdd(&lcnt[k], 1);
  __syncthreads();
  if (tid < kK) wsI[WS_CNT + blockIdx.x * kK + tid] = lcnt[tid];
  if (blockIdx.x == 0 && tid == 0) {
    wsI[WS_FLAGS]     = (s_bad > 8) ? 1 : 0;
    wsI[WS_FLAGS + 1] = is64 ? 1 : 0;
  }
}

// ---------------- kernel 2: scan (padded class bases) ------------------------
__global__ void scan_k(int* wsI) {
  __shared__ int cnts[NBLK * kK];
  __shared__ int tot[kK], pbs[kK];
  const int tid = threadIdx.x;
  for (int i = tid; i < NBLK * kK; i += 256) cnts[i] = wsI[WS_CNT + i];
  __syncthreads();
  if (tid < kK) {
    int s = 0;
    for (int b = 0; b < NBLK; ++b) s += cnts[b * kK + tid];
    tot[tid] = s;
  }
  __syncthreads();
  if (tid == 0) {
    int tiles = 0;
    for (int k = 0; k < kK; ++k) {
      pbs[k] = tiles * MT;                 // padded slot base
      tiles += (tot[k] + MT - 1) / MT;
      wsI[k] = tot[k];
    }
  }
  __syncthreads();
  if (tid < kK) {
    int r = pbs[tid];
    for (int b = 0; b < NBLK; ++b) { int t = cnts[b * kK + tid]; cnts[b * kK + tid] = r; r += t; }
  }
  __syncthreads();
  for (int i = tid; i < NBLK * kK; i += 256) wsI[WS_CNT + i] = cnts[i];
}

// ---------------- kernel 3: place + gather-transpose -------------------------
// Assign slots; write bucket[slot]=pixel; transpose x (coalesced reads) into
// Act0[slot][c] bf16 rows (full-line 256B scattered writes).
template<typename T>
__device__ __forceinline__ void stage_sub(const T* x, size_t base, int s,
                                          unsigned short (*Xt)[kC + 8], int tid);
template<>
__device__ __forceinline__ void stage_sub<__hip_bfloat16>(const __hip_bfloat16* x,
    size_t base, int s, unsigned short (*Xt)[kC + 8], int tid) {
  const unsigned short* xs = (const unsigned short*)x;
#pragma unroll
  for (int cc = 0; cc < 4; ++cc) {
    const int c  = cc * 32 + (tid >> 3);
    const int px = (tid & 7) * 8;
    bf16x8 v = *reinterpret_cast<const bf16x8*>(xs + base + (size_t)c * kHW + s * MT + px);
#pragma unroll
    for (int j = 0; j < 8; ++j) Xt[px + j][c] = (unsigned short)v[j];
  }
}
template<>
__device__ __forceinline__ void stage_sub<float>(const float* x,
    size_t base, int s, unsigned short (*Xt)[kC + 8], int tid) {
#pragma unroll
  for (int i = 0; i < 8; ++i) {
    const int flat = i * 256 + tid;
    const int c  = flat >> 4;
    const int P0 = (flat & 15) * 4;
    const float4 v = *reinterpret_cast<const float4*>(x + base + (size_t)c * kHW + s * MT + P0);
    const float vv[4] = {v.x, v.y, v.z, v.w};
#pragma unroll
    for (int j = 0; j < 4; ++j) Xt[P0 + j][c] = f2bf(vv[j]);
  }
}

__global__ __launch_bounds__(256) void placeg(const void* xraw, const void* segraw,
                                              int* wsI, int useAct) {
  __shared__ int lcnt[kK], lbase[kK], slotv[256];
  __shared__ unsigned short Xt[MT][kC + 8];
  const int tid = threadIdx.x, blk = blockIdx.x;
  const int isf32 = wsI[WS_FLAGS], is64 = wsI[WS_FLAGS + 1];
  if (tid < kK) { lcnt[tid] = 0; lbase[tid] = wsI[WS_CNT + blk * kK + tid]; }
  __syncthreads();
  const int p = blk * 256 + tid;
  const int k = is64 ? (int)((const long long*)segraw)[p] : ((const int*)segraw)[p];
  const int li = atomicAdd(&lcnt[k], 1);
  const int slot = lbase[k] + li;
  slotv[tid] = slot;
  (wsI + WS_BUCKET)[slot] = p;
  if (!useAct) return;

  const int bb  = (blk * 256) / kHW;
  const int hw0 = blk * 256 - bb * kHW;
  const size_t base = (size_t)bb * kC * kHW + hw0;
  unsigned short* Act = (unsigned short*)((char*)wsI + ACT_OFF);
#pragma unroll
  for (int s = 0; s < 4; ++s) {
    __syncthreads();
    if (isf32) stage_sub<float>((const float*)xraw, base, s, Xt, tid);
    else       stage_sub<__hip_bfloat16>((const __hip_bfloat16*)xraw, base, s, Xt, tid);
    __syncthreads();
    const int i = tid >> 2, q = tid & 3;
    const int dslot = slotv[s * MT + i];
    unsigned short* drow = Act + (size_t)dslot * kC;
#pragma unroll
    for (int m = 0; m < 4; ++m) {
      bf16x8 v = *reinterpret_cast<const bf16x8*>(&Xt[i][q * 32 + m * 8]);
      *reinterpret_cast<bf16x8*>(drow + q * 32 + m * 8) = v;
    }
  }
}

// ---------------- MFMA layer: dst = op(W @ src + b [+ dst]) ------------------
// A[m=lane&15][k=quad*8+j] from weight rows; B[n=pix][k] from swizzled LDS.
// D: col=lane&15 (pixel), row=quad*4+reg (channel) [m89-verified].
template<typename T, bool LRELU, bool RES>
__device__ __forceinline__ void layerD(const unsigned short (*src)[kC],
                                       unsigned short (*dst)[kC],
                                       const T* __restrict__ Wk,
                                       const T* __restrict__ bk, int tid) {
  const int wave = tid >> 6, lane = tid & 63, quad = lane >> 4, col = lane & 15;
  bf16x8 a[2][4];
  float bias[2][4];
#pragma unroll
  for (int oi = 0; oi < 2; ++oi) {
    const int row = (wave * 2 + oi) * 16 + col;
#pragma unroll
    for (int ks = 0; ks < 4; ++ks)
      a[oi][ks] = load_wfrag(Wk + (size_t)row * kC + ks * 32 + quad * 8);
#pragma unroll
    for (int r = 0; r < 4; ++r)
      bias[oi][r] = load1(bk + (wave * 2 + oi) * 16 + quad * 4 + r);
  }
#pragma unroll
  for (int pt = 0; pt < 4; ++pt) {
    const int pix = pt * 16 + col;
    bf16x8 b[4];
#pragma unroll
    for (int ks = 0; ks < 4; ++ks)
      b[ks] = *reinterpret_cast<const bf16x8*>(&src[pix][xgrp(pix, ks * 4 + quad) * 8]);
#pragma unroll
    for (int oi = 0; oi < 2; ++oi) {
      f32x4 acc = {0.f, 0.f, 0.f, 0.f};
#pragma unroll
      for (int ks = 0; ks < 4; ++ks)
        acc = __builtin_amdgcn_mfma_f32_16x16x32_bf16(a[oi][ks], b[ks], acc, 0, 0, 0);
      const int nb = (wave * 2 + oi) * 16 + quad * 4;
      unsigned short* dp = &dst[pix][xgrp(pix, nb >> 3) * 8 + (nb & 7)];
      float v[4];
#pragma unroll
      for (int r = 0; r < 4; ++r) {
        float t = acc[r] + bias[oi][r];
        if constexpr (LRELU) t = (t >= 0.f) ? t : kSlope * t;
        v[r] = t;
      }
      if constexpr (RES) {   // in-place residual: this 8B owned by this lane
        const short4 rv = *reinterpret_cast<const short4*>(dp);
        v[0] += bf2f((unsigned short)rv.x);
        v[1] += bf2f((unsigned short)rv.y);
        v[2] += bf2f((unsigned short)rv.z);
        v[3] += bf2f((unsigned short)rv.w);
      }
      short4 pk;
      pk.x = (short)f2bf(v[0]); pk.y = (short)f2bf(v[1]);
      pk.z = (short)f2bf(v[2]); pk.w = (short)f2bf(v[3]);
      *reinterpret_cast<short4*>(dp) = pk;
    }
  }
}

// final layer (60 outs) + scatter
template<typename T>
__device__ __forceinline__ void layer_out(const unsigned short (*src)[kC],
                                          const T* __restrict__ Wk,
                                          const T* __restrict__ bk,
                                          T* __restrict__ out,
                                          const int* spix, int nv, int tid) {
  const int wave = tid >> 6, lane = tid & 63, quad = lane >> 4, col = lane & 15;
  bf16x8 a[4];
  const int row = min(wave * 16 + col, kO - 1);
#pragma unroll
  for (int ks = 0; ks < 4; ++ks)
    a[ks] = load_wfrag(Wk + (size_t)row * kC + ks * 32 + quad * 8);
  float bias[4];
#pragma unroll
  for (int r = 0; r < 4; ++r) {
    const int n = wave * 16 + quad * 4 + r;
    bias[r] = (n < kO) ? load1(bk + n) : 0.f;
  }
#pragma unroll
  for (int pt = 0; pt < 4; ++pt) {
    const int pix = pt * 16 + col;
    bf16x8 b[4];
#pragma unroll
    for (int ks = 0; ks < 4; ++ks)
      b[ks] = *reinterpret_cast<const bf16x8*>(&src[pix][xgrp(pix, ks * 4 + quad) * 8]);
    f32x4 acc = {0.f, 0.f, 0.f, 0.f};
#pragma unroll
    for (int ks = 0; ks < 4; ++ks)
      acc = __builtin_amdgcn_mfma_f32_16x16x32_bf16(a[ks], b[ks], acc, 0, 0, 0);
    if (pix < nv) {
      const int p = spix[pix];
      const int bb = p / kHW;
      const int hw = p - bb * kHW;
      T* obase = out + (size_t)bb * kO * kHW + hw;
#pragma unroll
      for (int r = 0; r < 4; ++r) {
        const int n = wave * 16 + quad * 4 + r;
        if (n < kO) store1(obase + (size_t)n * kHW, acc[r] + bias[r]);
      }
    }
  }
}

// ---------------- kernel 4: chain ----------------
template<typename T>
__device__ void chain_body(const T* __restrict__ x,
                           const T* __restrict__ W1, const T* __restrict__ b1,
                           const T* __restrict__ Wr1, const T* __restrict__ br1,
                           const T* __restrict__ Wr2, const T* __restrict__ br2,
                           const T* __restrict__ W3, const T* __restrict__ b3,
                           const T* __restrict__ W4, const T* __restrict__ b4,
                           T* __restrict__ out, const int* wsI, int useAct,
                           unsigned short (*X)[kC], unsigned short (*Y)[kC],
                           int* spix) {
  const int tid = threadIdx.x, bid = blockIdx.x;
  int n[kK];
#pragma unroll
  for (int kk = 0; kk < kK; ++kk) n[kk] = wsI[kk];
  int k = -1, accT = 0, ti = 0;
#pragma unroll
  for (int kk = 0; kk < kK; ++kk) {
    const int tk = (n[kk] + MT - 1) / MT;
    if (k < 0 && bid < accT + tk) { k = kk; ti = bid - accT; }
    accT += tk;
  }
  if (k < 0) return;
  const int slot0 = bid * MT;           // padded bases make this exact
  const int nv = min(MT, n[k] - ti * MT);

  if (tid < MT) spix[tid] = (wsI + WS_BUCKET)[slot0 + tid];
  __syncthreads();

  if (useAct) {
    const unsigned short* Act = (const unsigned short*)((const char*)wsI + ACT_OFF);
    const int r = tid >> 2, q = tid & 3;
    const unsigned short* srow = Act + (size_t)(slot0 + r) * kC;
#pragma unroll
    for (int m = 0; m < 4; ++m) {
      const int g = q + m * 4;
      bf16x8 v = *reinterpret_cast<const bf16x8*>(srow + g * 8);
      *reinterpret_cast<bf16x8*>(&X[r][xgrp(r, g) * 8]) = v;
    }
  } else {
    // fallback: direct gather from x (uncoalesced; small-ws only)
    const int r = tid >> 2, q = tid & 3;
    const int p = spix[(r < nv) ? r : 0];
    const int bb = p / kHW;
    const int hw = p - bb * kHW;
    const size_t base = (size_t)bb * kC * kHW + hw;
#pragma unroll
    for (int j = 0; j < 32; ++j) {
      const int c = q * 32 + j;
      X[r][xgrp(r, c >> 3) * 8 + (c & 7)] = loadbf(x + base + (size_t)c * kHW);
    }
  }
  __syncthreads();

  const T* W1k  = W1  + (size_t)k * kC * kC;  const T* b1k  = b1  + (size_t)k * kC;
  const T* Wr1k = Wr1 + (size_t)k * kC * kC;  const T* br1k = br1 + (size_t)k * kC;
  const T* Wr2k = Wr2 + (size_t)k * kC * kC;  const T* br2k = br2 + (size_t)k * kC;
  const T* W3k  = W3  + (size_t)k * kC * kC;  const T* b3k  = b3  + (size_t)k * kC;
  const T* W4k  = W4  + (size_t)k * kO * kC;  const T* b4k  = b4  + (size_t)k * kO;

  layerD<T, false, false>(X, Y, W1k,  b1k,  tid); __syncthreads(); // Y = h
  layerD<T, true,  false>(Y, X, Wr1k, br1k, tid); __syncthreads(); // X = lrelu
  layerD<T, false, true >(X, Y, Wr2k, br2k, tid); __syncthreads(); // Y = h + r
  layerD<T, true,  false>(Y, X, W3k,  b3k,  tid); __syncthreads(); // X = lrelu
  layer_out<T>(X, W4k, b4k, out, spix, nv, tid);
}

__global__ __launch_bounds__(256, 4) void chain_kernel(
    const void* x, const void* W1, const void* b1, const void* Wr1, const void* br1,
    const void* Wr2, const void* br2, const void* W3, const void* b3,
    const void* W4, const void* b4, void* out, int* wsI, int useAct) {
  __shared__ unsigned short X[MT][kC];   // 16 KB
  __shared__ unsigned short Y[MT][kC];   // 16 KB
  __shared__ int spix[MT];
  if (wsI[WS_FLAGS]) {
    chain_body<float>((const float*)x,
                      (const float*)W1, (const float*)b1,
                      (const float*)Wr1, (const float*)br1,
                      (const float*)Wr2, (const float*)br2,
                      (const float*)W3, (const float*)b3,
                      (const float*)W4, (const float*)b4,
                      (float*)out, wsI, useAct, X, Y, spix);
  } else {
    chain_body<__hip_bfloat16>((const __hip_bfloat16*)x,
                               (const __hip_bfloat16*)W1, (const __hip_bfloat16*)b1,
                               (const __hip_bfloat16*)Wr1, (const __hip_bfloat16*)br1,
                               (const __hip_bfloat16*)Wr2, (const __hip_bfloat16*)br2,
                               (const __hip_bfloat16*)W3, (const __hip_bfloat16*)b3,
                               (const __hip_bfloat16*)W4, (const __hip_bfloat16*)b4,
                               (__hip_bfloat16*)out, wsI, useAct, X, Y, spix);
  }
}

extern "C" void kernel_launch(void* const* d_in, const int* in_sizes, int n_in,
                              void* d_out, int out_size, void* d_ws, size_t ws_size,
                              hipStream_t stream) {
  (void)in_sizes; (void)n_in; (void)out_size;
  int* wsI = (int*)d_ws;
  const int useAct = (ws_size >= ACT_OFF + ACT_BYTES) ? 1 : 0;
  count_sniff<<<NBLK, 256, 0, stream>>>(d_in[0], d_in[1], wsI);
  scan_k<<<1, 256, 0, stream>>>(wsI);
  placeg<<<NBLK, 256, 0, stream>>>(d_in[0], d_in[1], wsI, useAct);
  chain_kernel<<<NT + kK, 256, 0, stream>>>(
      d_in[0], d_in[2], d_in[3], d_in[4], d_in[5], d_in[6], d_in[7],
      d_in[8], d_in[9], d_in[10], d_in[11], d_out, wsI, useAct);
}